// Round 7
// baseline (31.555 us; speedup 1.0000x reference)
//
#include <hip/hip_runtime.h>

// 5x5 lower-median filter, reflect padding, fp32 in/out, x: [8,3,512,512]
// R7: packed-fp16 via __builtin_elementwise_min/max (native v_pk_min/max_f16
// ISel, no inline-asm copy constraints), 1-wave blocks for scheduling
// granularity. Window packing: lo half = window x0+B, hi = window x0+4+B.
static constexpr int H = 512, W = 512;
static constexpr int QX_I = 62, R_I = 254;           // interior 8x2 tiles/img
static constexpr int TILES_I = QX_I * R_I;           // 15748
static constexpr int BLK = 64;
static constexpr int IB = (TILES_I + BLK - 1) / BLK; // 247 interior blocks/img
static constexpr int EDGE_N = 2 * 256 + 2 * QX_I;    // 636 edge tiles/img
static constexpr int EB = (EDGE_N + BLK - 1) / BLK;  // 10 edge blocks/img

typedef __fp16 h2 __attribute__((ext_vector_type(2)));   // matches cvt_pkrtz return
typedef float f4u __attribute__((ext_vector_type(4), aligned(4)));
typedef float f4a __attribute__((ext_vector_type(4), aligned(16)));

// packed comparators -> v_pk_min_f16 / v_pk_max_f16 (native ISel)
__device__ __forceinline__ h2 PMN(h2 a, h2 b) { return __builtin_elementwise_min(a, b); }
__device__ __forceinline__ h2 PMX(h2 a, h2 b) { return __builtin_elementwise_max(a, b); }
__device__ __forceinline__ void PCE(h2& a, h2& b) {
    h2 lo = PMN(a, b), hi = PMX(a, b); a = lo; b = hi;
}
// med3(t,u,x) given u <= t  ==  max(u, min(t,x))
__device__ __forceinline__ h2 IMD(h2 t, h2 u, h2 x) { return PMX(u, PMN(t, x)); }

// Lower median (rank 12 of 25) for pack-window B: lo half = window at cols
// B..B+4, hi half = window at cols B+4..B+8 of the column-sorted packs S.
// Stage 1: sorted-column row exclusion -> sorted runs A2,B3,C3,D3,E2.
// Stage 2: G=merge(A,E); F=merge(B,C); H=merge(D,G); rank-7-of-13 identity.
template<int B>
__device__ __forceinline__ h2 med25p(const h2 S[5][8]) {
    // rowA (col minima): keep top2, u<=t
    h2 u = PMN(S[0][B], S[0][B+1]), t = PMX(S[0][B], S[0][B+1]);
    u = IMD(t, u, S[0][B+2]); t = PMX(t, S[0][B+2]);
    u = IMD(t, u, S[0][B+3]); t = PMX(t, S[0][B+3]);
    u = IMD(t, u, S[0][B+4]); t = PMX(t, S[0][B+4]);
    h2 A0 = u, A1 = t;
    // rowB: keep top3 sorted l<=m<=h
    h2 mn1 = PMN(S[1][B], S[1][B+1]), mx1 = PMX(S[1][B], S[1][B+1]);
    h2 l = PMN(mn1, S[1][B+2]), h = PMX(mx1, S[1][B+2]);
    h2 m = PMX(mn1, PMN(mx1, S[1][B+2]));
    { h2 x = S[1][B+3]; h2 nl = IMD(m,l,x), nm = IMD(h,m,x), nh = PMX(h,x); l=nl; m=nm; h=nh; }
    { h2 x = S[1][B+4]; h2 nl = IMD(m,l,x), nm = IMD(h,m,x), nh = PMX(h,x); l=nl; m=nm; h=nh; }
    h2 B0 = l, B1 = m, B2 = h;
    // rowC (col medians): keep middle3
    h2 mn2 = PMN(S[2][B], S[2][B+1]), mx2 = PMX(S[2][B], S[2][B+1]);
    h2 l2 = PMN(mn2, S[2][B+2]), hh = PMX(mx2, S[2][B+2]);
    h2 m2 = PMX(mn2, PMN(mx2, S[2][B+2]));
    h2 d4 = S[2][B+3];
    h2 s0 = PMN(l2, d4), s1 = IMD(m2, l2, d4), s2 = IMD(hh, m2, d4), s3 = PMX(hh, d4);
    h2 e4 = S[2][B+4];
    h2 C0 = IMD(s1, s0, e4), C1 = IMD(s2, s1, e4), C2 = IMD(s3, s2, e4);
    // rowD: keep bottom3
    h2 mn3 = PMN(S[3][B], S[3][B+1]), mx3 = PMX(S[3][B], S[3][B+1]);
    h2 l3 = PMN(mn3, S[3][B+2]), h3 = PMX(mx3, S[3][B+2]);
    h2 m3 = PMX(mn3, PMN(mx3, S[3][B+2]));
    { h2 x = S[3][B+3]; h2 nl = PMN(l3,x), nm = IMD(m3,l3,x), nh = IMD(h3,m3,x); l3=nl; m3=nm; h3=nh; }
    { h2 x = S[3][B+4]; h2 nl = PMN(l3,x), nm = IMD(m3,l3,x), nh = IMD(h3,m3,x); l3=nl; m3=nm; h3=nh; }
    h2 D0 = l3, D1 = m3, D2 = h3;
    // rowE (col maxima): keep bottom2, p<=q
    h2 p = PMN(S[4][B], S[4][B+1]), q = PMX(S[4][B], S[4][B+1]);
    q = IMD(q, p, S[4][B+2]); p = PMN(p, S[4][B+2]);
    q = IMD(q, p, S[4][B+3]); p = PMN(p, S[4][B+3]);
    q = IMD(q, p, S[4][B+4]); p = PMN(p, S[4][B+4]);
    h2 E0 = p, E1 = q;

    // G4 = merge(A2, E2): (A0,E0,A1,E1)
    PCE(A0, E0); PCE(A1, E1); PCE(E0, A1);
    h2 G0 = A0, G1 = E0, G2 = A1, G3 = E1;
    // F6 = merge(B3, C3): odd-even merge -> (B0,B1,C0,C1,B2,C2)
    PCE(B0, C0); PCE(B2, C2); PCE(C0, B2);
    PCE(B1, C1);
    PCE(B1, C0); PCE(C1, B2);
    h2 F0 = B0, F1 = B1, F2 = C0, F3 = C1, F4 = B2, F5 = C2;
    // H7 = merge(D3, G4): odd-even merge -> (D0,D1,G0,G1,D2,G3,G2)
    PCE(D0, G0); PCE(D2, G2); PCE(G0, D2);
    PCE(D1, G1); PCE(G1, G3);
    PCE(D1, G0); PCE(G1, D2); PCE(G3, G2);
    h2 H0 = D0, H1 = D1, H2 = G0, H3 = G1, H4 = D2, H5 = G3, H6 = G2;
    // median of 13 = 7th smallest of F(6) U H(7) = min over i+j=7 of max(F[i-1],H[j-1])
    h2 r = PMN(H6, PMX(F0, H5));
    r = PMN(r, PMX(F1, H4));
    r = PMN(r, PMX(F2, H3));
    r = PMN(r, PMX(F3, H2));
    r = PMN(r, PMX(F4, H1));
    r = PMN(r, PMX(F5, H0));
    return r;
}

// one output row: insert edge row xr into sorted-4 columns, run 4 pack-windows
__device__ __forceinline__ void do_row(const h2* q0, const h2* q1, const h2* q2, const h2* q3,
                                       const h2* xr, float* outp) {
    h2 T[5][8];
    #pragma unroll
    for (int k = 0; k < 8; ++k) {
        h2 x = xr[k];
        T[0][k] = PMN(q0[k], x);
        T[1][k] = IMD(q1[k], q0[k], x);
        T[2][k] = IMD(q2[k], q1[k], x);
        T[3][k] = IMD(q3[k], q2[k], x);
        T[4][k] = PMX(q3[k], x);
    }
    h2 r0 = med25p<0>(T), r1 = med25p<1>(T), r2 = med25p<2>(T), r3 = med25p<3>(T);
    f4a lo, hi;
    lo.x = (float)r0.x; lo.y = (float)r1.x; lo.z = (float)r2.x; lo.w = (float)r3.x;
    hi.x = (float)r0.y; hi.y = (float)r1.y; hi.z = (float)r2.y; hi.w = (float)r3.y;
    *(f4a*)outp = lo;
    *(f4a*)(outp + 4) = hi;
}

__device__ __forceinline__ int refl(int z, int n) {
    z = (z < 0) ? -z : z;
    return (z >= n) ? 2 * n - 2 - z : z;
}

__global__ __launch_bounds__(BLK, 4) void median5x5_kernel(const float* __restrict__ in,
                                                           float* __restrict__ out) {
    int bc = blockIdx.y;
    const float* __restrict__ img = in + (size_t)bc * (H * W);
    float* __restrict__ outc = out + (size_t)bc * (H * W);

    h2 P[6][8];       // packed cols: P[r][k] = (col k, col k+4), abs col = x0-2+k
    int x0, y0;
    if ((int)blockIdx.x < IB) {
        int i = blockIdx.x * BLK + threadIdx.x;
        if (i >= TILES_I) return;
        int r  = i / QX_I;
        int qx = i - r * QX_I;
        x0 = 8 * (qx + 1);           // 8..496
        y0 = 2 * (r + 1);            // 2..508
        const float* p0 = img + (y0 - 2) * W + (x0 - 2);
        #pragma unroll
        for (int rr = 0; rr < 6; ++rr) {
            f4u a = *(const f4u*)(p0 + rr * W);
            f4u b = *(const f4u*)(p0 + rr * W + 4);
            f4u c = *(const f4u*)(p0 + rr * W + 8);
            P[rr][0] = __builtin_amdgcn_cvt_pkrtz(a.x, b.x);
            P[rr][1] = __builtin_amdgcn_cvt_pkrtz(a.y, b.y);
            P[rr][2] = __builtin_amdgcn_cvt_pkrtz(a.z, b.z);
            P[rr][3] = __builtin_amdgcn_cvt_pkrtz(a.w, b.w);
            P[rr][4] = __builtin_amdgcn_cvt_pkrtz(b.x, c.x);
            P[rr][5] = __builtin_amdgcn_cvt_pkrtz(b.y, c.y);
            P[rr][6] = __builtin_amdgcn_cvt_pkrtz(b.z, c.z);
            P[rr][7] = __builtin_amdgcn_cvt_pkrtz(b.w, c.w);
        }
    } else {
        int j = ((int)blockIdx.x - IB) * BLK + threadIdx.x;
        if (j >= EDGE_N) return;
        int qx, r;
        if (j < 512) { qx = (j & 1) ? 63 : 0; r = j >> 1; }
        else {
            int k2 = j - 512;
            if (k2 < QX_I) { r = 0;   qx = k2 + 1; }
            else           { r = 255; qx = k2 - (QX_I - 1); }
        }
        x0 = 8 * qx; y0 = 2 * r;
        int ry[6], rx[12];
        #pragma unroll
        for (int i2 = 0; i2 < 6; ++i2) ry[i2] = refl(y0 - 2 + i2, H);
        #pragma unroll
        for (int k = 0; k < 12; ++k) rx[k] = refl(x0 - 2 + k, W);
        #pragma unroll
        for (int rr = 0; rr < 6; ++rr) {
            float tmp[12];
            #pragma unroll
            for (int k = 0; k < 12; ++k) tmp[k] = img[ry[rr] * W + rx[k]];
            #pragma unroll
            for (int k = 0; k < 8; ++k)
                P[rr][k] = __builtin_amdgcn_cvt_pkrtz(tmp[k], tmp[k + 4]);
        }
    }

    // sorted-4 of shared rows 1..4, per packed column
    h2 q0[8], q1[8], q2[8], q3[8];
    #pragma unroll
    for (int k = 0; k < 8; ++k) {
        h2 a = P[1][k], b = P[2][k], c = P[3][k], d = P[4][k];
        h2 mn = PMN(a, b), mx = PMX(a, b);
        h2 l = PMN(mn, c), hh = PMX(mx, c);
        h2 m = PMX(mn, PMN(mx, c));
        q0[k] = PMN(l, d); q1[k] = IMD(m, l, d); q2[k] = IMD(hh, m, d); q3[k] = PMX(hh, d);
    }
    do_row(q0, q1, q2, q3, P[0], outc + y0 * W + x0);
    do_row(q0, q1, q2, q3, P[5], outc + (y0 + 1) * W + x0);
}

extern "C" void kernel_launch(void* const* d_in, const int* in_sizes, int n_in,
                              void* d_out, int out_size, void* d_ws, size_t ws_size,
                              hipStream_t stream) {
    const float* x = (const float*)d_in[0];
    float* out = (float*)d_out;
    int n_bc = in_sizes[0] / (H * W);       // 24
    dim3 grid(IB + EB, n_bc, 1);
    median5x5_kernel<<<grid, BLK, 0, stream>>>(x, out);
}

// Round 8
// 28.518 us; speedup vs baseline: 1.1065x; 1.1065x over previous
//
#include <hip/hip_runtime.h>

// 5x5 lower-median filter, reflect padding, fp32 in/out, x: [8,3,512,512]
// R8: R6 asm packed-fp16 comparators + 256-thread blocks (proven best),
// restructured for low register pressure (stream edge rows after q-build),
// __launch_bounds__(256,4) for 4 waves/SIMD, 16B-aligned loads.
static constexpr int H = 512, W = 512;
static constexpr int QX_I = 62, R_I = 254;           // interior 8x2 tiles/img
static constexpr int TILES_I = QX_I * R_I;           // 15748
static constexpr int IB = (TILES_I + 255) / 256;     // 62 interior blocks/img
static constexpr int EDGE_N = 2 * 256 + 2 * QX_I;    // 636 edge tiles/img
static constexpr int EB = (EDGE_N + 255) / 256;      // 3 edge blocks/img

typedef __fp16 h2 __attribute__((ext_vector_type(2)));
typedef float f4 __attribute__((ext_vector_type(4), aligned(16)));
typedef float f4a __attribute__((ext_vector_type(4), aligned(16)));

// packed single-instruction comparators (non-volatile asm: CSE/schedulable)
__device__ __forceinline__ h2 PMN(h2 a, h2 b) {
    h2 d; asm("v_pk_min_f16 %0, %1, %2" : "=v"(d) : "v"(a), "v"(b)); return d;
}
__device__ __forceinline__ h2 PMX(h2 a, h2 b) {
    h2 d; asm("v_pk_max_f16 %0, %1, %2" : "=v"(d) : "v"(a), "v"(b)); return d;
}
__device__ __forceinline__ void PCE(h2& a, h2& b) {
    h2 lo = PMN(a, b), hi = PMX(a, b); a = lo; b = hi;
}
// med3(t,u,x) given u <= t  ==  max(u, min(t,x))
__device__ __forceinline__ h2 IMD(h2 t, h2 u, h2 x) { return PMX(u, PMN(t, x)); }

// Lower median (rank 12 of 25) for pack-window B: lo half = window at cols
// B..B+4, hi half = window at cols B+4..B+8 of column-sorted packs S[5][8].
template<int B>
__device__ __forceinline__ h2 med25p(const h2 S[5][8]) {
    // rowA (col minima): keep top2, u<=t
    h2 u = PMN(S[0][B], S[0][B+1]), t = PMX(S[0][B], S[0][B+1]);
    u = IMD(t, u, S[0][B+2]); t = PMX(t, S[0][B+2]);
    u = IMD(t, u, S[0][B+3]); t = PMX(t, S[0][B+3]);
    u = IMD(t, u, S[0][B+4]); t = PMX(t, S[0][B+4]);
    h2 A0 = u, A1 = t;
    // rowB: keep top3 sorted l<=m<=h
    h2 mn1 = PMN(S[1][B], S[1][B+1]), mx1 = PMX(S[1][B], S[1][B+1]);
    h2 l = PMN(mn1, S[1][B+2]), h = PMX(mx1, S[1][B+2]);
    h2 m = PMX(mn1, PMN(mx1, S[1][B+2]));
    { h2 x = S[1][B+3]; h2 nl = IMD(m,l,x), nm = IMD(h,m,x), nh = PMX(h,x); l=nl; m=nm; h=nh; }
    { h2 x = S[1][B+4]; h2 nl = IMD(m,l,x), nm = IMD(h,m,x), nh = PMX(h,x); l=nl; m=nm; h=nh; }
    h2 B0 = l, B1 = m, B2 = h;
    // rowC (col medians): keep middle3
    h2 mn2 = PMN(S[2][B], S[2][B+1]), mx2 = PMX(S[2][B], S[2][B+1]);
    h2 l2 = PMN(mn2, S[2][B+2]), hh = PMX(mx2, S[2][B+2]);
    h2 m2 = PMX(mn2, PMN(mx2, S[2][B+2]));
    h2 d4 = S[2][B+3];
    h2 s0 = PMN(l2, d4), s1 = IMD(m2, l2, d4), s2 = IMD(hh, m2, d4), s3 = PMX(hh, d4);
    h2 e4 = S[2][B+4];
    h2 C0 = IMD(s1, s0, e4), C1 = IMD(s2, s1, e4), C2 = IMD(s3, s2, e4);
    // rowD: keep bottom3
    h2 mn3 = PMN(S[3][B], S[3][B+1]), mx3 = PMX(S[3][B], S[3][B+1]);
    h2 l3 = PMN(mn3, S[3][B+2]), h3 = PMX(mx3, S[3][B+2]);
    h2 m3 = PMX(mn3, PMN(mx3, S[3][B+2]));
    { h2 x = S[3][B+3]; h2 nl = PMN(l3,x), nm = IMD(m3,l3,x), nh = IMD(h3,m3,x); l3=nl; m3=nm; h3=nh; }
    { h2 x = S[3][B+4]; h2 nl = PMN(l3,x), nm = IMD(m3,l3,x), nh = IMD(h3,m3,x); l3=nl; m3=nm; h3=nh; }
    h2 D0 = l3, D1 = m3, D2 = h3;
    // rowE (col maxima): keep bottom2, p<=q
    h2 p = PMN(S[4][B], S[4][B+1]), q = PMX(S[4][B], S[4][B+1]);
    q = IMD(q, p, S[4][B+2]); p = PMN(p, S[4][B+2]);
    q = IMD(q, p, S[4][B+3]); p = PMN(p, S[4][B+3]);
    q = IMD(q, p, S[4][B+4]); p = PMN(p, S[4][B+4]);
    h2 E0 = p, E1 = q;

    // G4 = merge(A2, E2): (A0,E0,A1,E1)
    PCE(A0, E0); PCE(A1, E1); PCE(E0, A1);
    h2 G0 = A0, G1 = E0, G2 = A1, G3 = E1;
    // F6 = merge(B3, C3): odd-even merge -> (B0,B1,C0,C1,B2,C2)
    PCE(B0, C0); PCE(B2, C2); PCE(C0, B2);
    PCE(B1, C1);
    PCE(B1, C0); PCE(C1, B2);
    h2 F0 = B0, F1 = B1, F2 = C0, F3 = C1, F4 = B2, F5 = C2;
    // H7 = merge(D3, G4): odd-even merge -> (D0,D1,G0,G1,D2,G3,G2)
    PCE(D0, G0); PCE(D2, G2); PCE(G0, D2);
    PCE(D1, G1); PCE(G1, G3);
    PCE(D1, G0); PCE(G1, D2); PCE(G3, G2);
    h2 H0 = D0, H1 = D1, H2 = G0, H3 = G1, H4 = D2, H5 = G3, H6 = G2;
    // median of 13 = 7th of F(6) U H(7) = min over i+j=7 of max(F[i-1],H[j-1])
    h2 r = PMN(H6, PMX(F0, H5));
    r = PMN(r, PMX(F1, H4));
    r = PMN(r, PMX(F2, H3));
    r = PMN(r, PMX(F3, H2));
    r = PMN(r, PMX(F4, H1));
    r = PMN(r, PMX(F5, H0));
    return r;
}

// one output row: insert edge row xr into sorted-4 columns, run 4 pack-windows
__device__ __forceinline__ void do_row(const h2* q0, const h2* q1, const h2* q2, const h2* q3,
                                       const h2* xr, float* outp) {
    h2 T[5][8];
    #pragma unroll
    for (int k = 0; k < 8; ++k) {
        h2 x = xr[k];
        T[0][k] = PMN(q0[k], x);
        T[1][k] = IMD(q1[k], q0[k], x);
        T[2][k] = IMD(q2[k], q1[k], x);
        T[3][k] = IMD(q3[k], q2[k], x);
        T[4][k] = PMX(q3[k], x);
    }
    h2 r0 = med25p<0>(T), r1 = med25p<1>(T), r2 = med25p<2>(T), r3 = med25p<3>(T);
    f4a lo, hi;
    lo.x = (float)r0.x; lo.y = (float)r1.x; lo.z = (float)r2.x; lo.w = (float)r3.x;
    hi.x = (float)r0.y; hi.y = (float)r1.y; hi.z = (float)r2.y; hi.w = (float)r3.y;
    *(f4a*)outp = lo;
    *(f4a*)(outp + 4) = hi;
}

// aligned row load (base = row + x0 - 4, 16B-aligned) + pack to 8 h2
// pack[k] = (col x0-2+k, col x0+2+k) = (f[k+2], f[k+6]) of the 16 floats
__device__ __forceinline__ void loadrow_pack(const float* p, h2 out[8]) {
    f4 A = *(const f4*)p;
    f4 Bv = *(const f4*)(p + 4);
    f4 C = *(const f4*)(p + 8);
    f4 D = *(const f4*)(p + 12);
    out[0] = __builtin_amdgcn_cvt_pkrtz(A.z,  Bv.z);
    out[1] = __builtin_amdgcn_cvt_pkrtz(A.w,  Bv.w);
    out[2] = __builtin_amdgcn_cvt_pkrtz(Bv.x, C.x);
    out[3] = __builtin_amdgcn_cvt_pkrtz(Bv.y, C.y);
    out[4] = __builtin_amdgcn_cvt_pkrtz(Bv.z, C.z);
    out[5] = __builtin_amdgcn_cvt_pkrtz(Bv.w, C.w);
    out[6] = __builtin_amdgcn_cvt_pkrtz(C.x,  D.x);
    out[7] = __builtin_amdgcn_cvt_pkrtz(C.y,  D.y);
}

__device__ __forceinline__ int refl(int z, int n) {
    z = (z < 0) ? -z : z;
    return (z >= n) ? 2 * n - 2 - z : z;
}

__global__ __launch_bounds__(256, 4) void median5x5_kernel(const float* __restrict__ in,
                                                           float* __restrict__ out) {
    int bc = blockIdx.y;
    const float* __restrict__ img = in + (size_t)bc * (H * W);
    float* __restrict__ outc = out + (size_t)bc * (H * W);

    int x0, y0;
    h2 m1[8], m2[8], m3[8], m4[8];    // shared mid rows (y0-1..y0+2), packed
    h2 e0[8], e5[8];                  // edge rows (y0-2, y0+3), packed

    if ((int)blockIdx.x < IB) {
        int i = blockIdx.x * 256 + threadIdx.x;
        if (i >= TILES_I) return;
        int r  = i / QX_I;
        int qx = i - r * QX_I;
        x0 = 8 * (qx + 1);           // 8..496
        y0 = 2 * (r + 1);            // 2..508
        const float* base = img + (y0 - 2) * W + (x0 - 4);   // 16B aligned
        // mid rows first (live through q-build), edge rows streamed after
        loadrow_pack(base + 1 * W, m1);
        loadrow_pack(base + 2 * W, m2);
        loadrow_pack(base + 3 * W, m3);
        loadrow_pack(base + 4 * W, m4);
        loadrow_pack(base + 0 * W, e0);
        loadrow_pack(base + 5 * W, e5);
    } else {
        int j = ((int)blockIdx.x - IB) * 256 + threadIdx.x;
        if (j >= EDGE_N) return;
        int qx, r;
        if (j < 512) { qx = (j & 1) ? 63 : 0; r = j >> 1; }
        else {
            int k2 = j - 512;
            if (k2 < QX_I) { r = 0;   qx = k2 + 1; }
            else           { r = 255; qx = k2 - (QX_I - 1); }
        }
        x0 = 8 * qx; y0 = 2 * r;
        int ry[6], rx[12];
        #pragma unroll
        for (int i2 = 0; i2 < 6; ++i2) ry[i2] = refl(y0 - 2 + i2, H);
        #pragma unroll
        for (int k = 0; k < 12; ++k) rx[k] = refl(x0 - 2 + k, W);
        h2* rows[6] = { e0, m1, m2, m3, m4, e5 };
        #pragma unroll
        for (int rr = 0; rr < 6; ++rr) {
            float tmp[12];
            #pragma unroll
            for (int k = 0; k < 12; ++k) tmp[k] = img[ry[rr] * W + rx[k]];
            #pragma unroll
            for (int k = 0; k < 8; ++k)
                rows[rr][k] = __builtin_amdgcn_cvt_pkrtz(tmp[k], tmp[k + 4]);
        }
    }

    // sorted-4 of shared mid rows, per packed column (mid rows die here)
    h2 q0[8], q1[8], q2[8], q3[8];
    #pragma unroll
    for (int k = 0; k < 8; ++k) {
        h2 a = m1[k], b = m2[k], c = m3[k], d = m4[k];
        h2 mn = PMN(a, b), mx = PMX(a, b);
        h2 l = PMN(mn, c), hh = PMX(mx, c);
        h2 m = PMX(mn, PMN(mx, c));
        q0[k] = PMN(l, d); q1[k] = IMD(m, l, d); q2[k] = IMD(hh, m, d); q3[k] = PMX(hh, d);
    }
    do_row(q0, q1, q2, q3, e0, outc + y0 * W + x0);
    do_row(q0, q1, q2, q3, e5, outc + (y0 + 1) * W + x0);
}

extern "C" void kernel_launch(void* const* d_in, const int* in_sizes, int n_in,
                              void* d_out, int out_size, void* d_ws, size_t ws_size,
                              hipStream_t stream) {
    const float* x = (const float*)d_in[0];
    float* out = (float*)d_out;
    int n_bc = in_sizes[0] / (H * W);       // 24
    dim3 grid(IB + EB, n_bc, 1);
    median5x5_kernel<<<grid, 256, 0, stream>>>(x, out);
}